// Round 11
// baseline (3819.973 us; speedup 1.0000x reference)
//
#include <hip/hip_runtime.h>
#include <math.h>

#define B_TOT 256
#define L_SEQ 256
#define DM 256
#define DI 512
#define DS 16
#define NL 6
#define MLPH 128
#define ED 64

typedef unsigned short u16;
typedef unsigned int   u32;
using bf16x8 = __attribute__((ext_vector_type(8))) short;
using f32x4  = __attribute__((ext_vector_type(4))) float;
using f32x2  = __attribute__((ext_vector_type(2))) float;

__device__ __forceinline__ float f_sigmoid(float x){ return 1.f/(1.f+__expf(-x)); }
__device__ __forceinline__ float f_silu(float x){ return x/(1.f+__expf(-x)); }
__device__ __forceinline__ u16 f2bf(float x){
  union { float f; u32 u; } v; v.f = x;
  u32 r = v.u + 0x7fffu + ((v.u >> 16) & 1u);
  return (u16)(r >> 16);
}
__device__ __forceinline__ float bf2f(u16 h){
  union { u32 u; float f; } v; v.u = ((u32)h) << 16; return v.f;
}
__device__ __forceinline__ f32x2 unpk2(u32 v){
  union { u32 u; float f; } a, b;
  a.u = (v & 0xffffu) << 16; b.u = v & 0xffff0000u;
  f32x2 r; r.x = a.f; r.y = b.f; return r;
}
// async global->LDS, 16B per lane; lds dest = wave-uniform base + lane*16
__device__ __forceinline__ void gl_lds16(const u16* g, uint4* l){
  __builtin_amdgcn_global_load_lds(
      (const __attribute__((address_space(1))) void*)g,
      (__attribute__((address_space(3))) void*)l, 16, 0, 0);
}

// ---------- weight conversion: 4 arrays in one launch ----------
__global__ __launch_bounds__(256) void k_cvt4(
    const float* __restrict__ s0, int n0, const float* __restrict__ s1, int n1,
    const float* __restrict__ s2, int n2, const float* __restrict__ s3, int n3,
    u16* __restrict__ d)
{
  int i = blockIdx.x*256 + threadIdx.x;
  float v;
  if (i < n0) v = s0[i];
  else if (i < n0+n1) v = s1[i-n0];
  else if (i < n0+n1+n2) v = s2[i-n0-n1];
  else if (i < n0+n1+n2+n3) v = s3[i-n0-n1-n2];
  else return;
  d[i] = f2bf(v);
}
__global__ __launch_bounds__(256) void k_cvt_xproj(const float* __restrict__ s, u16* __restrict__ d){
  int i = blockIdx.x*256 + threadIdx.x;      // over NL*64*512
  int k = i & 511; int n = (i>>9) & 63; int l = i >> 15;
  d[i] = (n < 48) ? f2bf(s[((size_t)l*48 + n)*512 + k]) : (u16)0;
}

// ---------- embedding + conv(k=3) + affine + relu -> residual (bf16) ----------
__global__ __launch_bounds__(256) void k_embed_conv(
    const int* __restrict__ tok, const float* __restrict__ emb,
    const float* __restrict__ cw, const float* __restrict__ gamma,
    const float* __restrict__ beta, u16* __restrict__ out)
{
  const int b  = blockIdx.y;
  const int lt = blockIdx.x;
  const int tid = threadIdx.x;
  __shared__ float xs[18][ED];
  for (int idx = tid; idx < 18*ED; idx += 256){
    int t = idx / ED, i = idx - t*ED;
    int l = lt*16 + t - 1;
    float v = 0.f;
    if (l >= 0 && l < L_SEQ) v = emb[tok[b*L_SEQ + l]*ED + i];
    xs[t][i] = v;
  }
  __syncthreads();
  const float g  = gamma[tid] * rsqrtf(1.001f);
  const float bt = beta[tid];
  const float* w = cw + (size_t)tid*(ED*3);
  float acc[16];
  #pragma unroll
  for (int t=0;t<16;t++) acc[t]=0.f;
  for (int i=0;i<ED;i++){
    float w0 = w[i*3+0], w1 = w[i*3+1], w2 = w[i*3+2];
    #pragma unroll
    for (int t=0;t<16;t++)
      acc[t] += xs[t][i]*w0 + xs[t+1][i]*w1 + xs[t+2][i]*w2;
  }
  #pragma unroll
  for (int t=0;t<16;t++){
    float v = acc[t]*g + bt;
    out[((size_t)(b*L_SEQ + lt*16 + t))*DM + tid] = f2bf(fmaxf(v, 0.f));
  }
}

// ---------- rmsnorm of residual (bf16) -> bf16 (first layer only) ----------
__global__ __launch_bounds__(256) void k_rms_first(
    const u16* __restrict__ residual, const float* __restrict__ w, u16* __restrict__ out)
{
  const int row  = blockIdx.x*4 + (threadIdx.x >> 6);
  const int lane = threadIdx.x & 63;
  const size_t base = (size_t)row*DM;
  uint2 rv = *(const uint2*)(residual + base + lane*4);
  float v0 = bf2f((u16)(rv.x & 0xffff)), v1 = bf2f((u16)(rv.x >> 16));
  float v2 = bf2f((u16)(rv.y & 0xffff)), v3 = bf2f((u16)(rv.y >> 16));
  float ss = v0*v0 + v1*v1 + v2*v2 + v3*v3;
  #pragma unroll
  for (int m=1; m<64; m<<=1) ss += __shfl_xor(ss, m);
  const float sc = rsqrtf(ss*(1.f/DM) + 1e-4f);
  float4 wv = ((const float4*)w)[lane];
  u32 p0 = f2bf(v0*sc*wv.x) | ((u32)f2bf(v1*sc*wv.y) << 16);
  u32 p1 = f2bf(v2*sc*wv.z) | ((u32)f2bf(v3*sc*wv.w) << 16);
  uint2 pk; pk.x = p0; pk.y = p1;
  *(uint2*)(out + base + lane*4) = pk;
}

// ---------- final layernorm (residual bf16 in, f32 out) ----------
__global__ __launch_bounds__(256) void k_final_ln(
    const u16* __restrict__ x,
    const float* __restrict__ w, const float* __restrict__ bb, float* __restrict__ out)
{
  const int row  = blockIdx.x*4 + (threadIdx.x >> 6);
  const int lane = threadIdx.x & 63;
  const size_t base = (size_t)row*DM;
  uint2 rv = *(const uint2*)(x + base + lane*4);
  float4 v;
  v.x = bf2f((u16)(rv.x & 0xffff)); v.y = bf2f((u16)(rv.x >> 16));
  v.z = bf2f((u16)(rv.y & 0xffff)); v.w = bf2f((u16)(rv.y >> 16));
  float s = v.x + v.y + v.z + v.w;
  #pragma unroll
  for (int m=1; m<64; m<<=1) s += __shfl_xor(s, m);
  const float mu = s*(1.f/DM);
  float4 c; c.x=v.x-mu; c.y=v.y-mu; c.z=v.z-mu; c.w=v.w-mu;
  float ss = c.x*c.x + c.y*c.y + c.z*c.z + c.w*c.w;
  #pragma unroll
  for (int m=1; m<64; m<<=1) ss += __shfl_xor(ss, m);
  const float sc = rsqrtf(ss*(1.f/DM) + 1e-4f);
  float4 wv = ((const float4*)w)[lane];
  float4 bv = ((const float4*)bb)[lane];
  float4 o;
  o.x = c.x*sc*wv.x + bv.x; o.y = c.y*sc*wv.y + bv.y;
  o.z = c.z*sc*wv.z + bv.z; o.w = c.w*sc*wv.w + bv.w;
  ((float4*)(out + base))[lane] = o;
}

// ---------- bf16 MFMA GEMM (4 waves) with global_load_lds staging ----------
// LDS slot (r,c) holds global chunk c^(r&7); source pre-swizzled, dest linear.
template<int BN, bool BF16OUT, bool SWIZ>
__global__ __launch_bounds__(256) void k_gemm_bf(
    const u16* __restrict__ A, const u16* __restrict__ W,
    void* __restrict__ Cv, int Nc, int K, int nmb)
{
  int bx, by;
  if (SWIZ){
    const int id = blockIdx.x;
    const int xcd = id & 7, rem = id >> 3;
    const int per = nmb >> 3;
    by = xcd*per + (rem % per);
    bx = rem / per;
  } else { bx = blockIdx.x; by = blockIdx.y; }
  const int n0 = bx * BN;
  const int m0 = by * 128;
  const int tid = threadIdx.x;
  const int wv = tid >> 6, t = tid & 63;
  const int wr = wv >> 1, wc = wv & 1;
  const int lr = t & 15, kb = t >> 4;
  constexpr int NJ = BN / 32;
  __shared__ uint4 As4[128*8];
  __shared__ uint4 Bs4[BN*8];
  f32x4 acc[4][NJ];
  #pragma unroll
  for (int i=0;i<4;i++)
    #pragma unroll
    for (int j=0;j<NJ;j++)
      acc[i][j] = (f32x4){0.f,0.f,0.f,0.f};
  const int lr8 = t >> 3, lc8 = t & 7;
  const int sc  = lc8 ^ lr8;            // pre-swizzled source chunk (r&7 == lr8)
  for (int k0 = 0; k0 < K; k0 += 64){
    #pragma unroll
    for (int i=0;i<4;i++){
      int r = i*32 + wv*8 + lr8;
      gl_lds16(A + (size_t)(m0 + r)*K + k0 + sc*8, &As4[(i*32 + wv*8)*8]);
    }
    #pragma unroll
    for (int i=0;i<BN/32;i++){
      int r = i*32 + wv*8 + lr8;
      gl_lds16(W + (size_t)(n0 + r)*K + k0 + sc*8, &Bs4[(i*32 + wv*8)*8]);
    }
    __syncthreads();
    #pragma unroll
    for (int kk=0;kk<2;kk++){
      bf16x8 af[4], bfr[NJ];
      #pragma unroll
      for (int mi=0;mi<4;mi++){
        int r = wr*64 + mi*16 + lr;
        af[mi] = *(const bf16x8*)&As4[r*8 + ((kk*4 + kb) ^ (r & 7))];
      }
      #pragma unroll
      for (int ni=0;ni<NJ;ni++){
        int r = wc*(BN/2) + ni*16 + lr;
        bfr[ni] = *(const bf16x8*)&Bs4[r*8 + ((kk*4 + kb) ^ (r & 7))];
      }
      #pragma unroll
      for (int mi=0;mi<4;mi++)
        #pragma unroll
        for (int ni=0;ni<NJ;ni++)
          acc[mi][ni] = __builtin_amdgcn_mfma_f32_16x16x32_bf16(af[mi], bfr[ni], acc[mi][ni], 0, 0, 0);
    }
    __syncthreads();
  }
  #pragma unroll
  for (int mi=0;mi<4;mi++){
    #pragma unroll
    for (int ni=0;ni<NJ;ni++){
      int col = n0 + wc*(BN/2) + ni*16 + lr;
      if (col < Nc){
        #pragma unroll
        for (int r=0;r<4;r++){
          size_t row = (size_t)(m0 + wr*64 + mi*16 + kb*4 + r);
          if (BF16OUT) ((u16*)Cv)[row*Nc + col] = f2bf(acc[mi][ni][r]);
          else         ((float*)Cv)[row*Nc + col] = acc[mi][ni][r];
        }
      }
    }
  }
}

// ---------- 8-wave GEMM (N=256) + residual(bf16) add + rmsnorm fused ----------
template<bool WRITE_HS>
__global__ __launch_bounds__(512) void k_gemm_rms(
    const u16* __restrict__ A, const u16* __restrict__ W,
    u16* __restrict__ residual, const float* __restrict__ nw,
    u16* __restrict__ hs, int K)
{
  const int m0 = blockIdx.x * 128;
  const int tid = threadIdx.x;
  const int wv = tid >> 6, t = tid & 63;
  const int wr = wv >> 1, wc = wv & 1;
  const int lr = t & 15, kb = t >> 4;
  __shared__ uint4 As4[128*8];
  __shared__ uint4 Bs4[256*8];
  __shared__ float red[128][2];
  f32x4 acc[2][8];
  #pragma unroll
  for (int i=0;i<2;i++)
    #pragma unroll
    for (int j=0;j<8;j++) acc[i][j] = (f32x4){0.f,0.f,0.f,0.f};
  const int lr8 = t >> 3, lc8 = t & 7;
  const int sc  = lc8 ^ lr8;
  for (int k0 = 0; k0 < K; k0 += 64){
    #pragma unroll
    for (int i=0;i<2;i++){
      int r = i*64 + wv*8 + lr8;
      gl_lds16(A + (size_t)(m0 + r)*K + k0 + sc*8, &As4[(i*64 + wv*8)*8]);
    }
    #pragma unroll
    for (int i=0;i<4;i++){
      int r = i*64 + wv*8 + lr8;
      gl_lds16(W + (size_t)r*K + k0 + sc*8, &Bs4[(i*64 + wv*8)*8]);
    }
    __syncthreads();
    #pragma unroll
    for (int kk=0;kk<2;kk++){
      bf16x8 af[2], bfr[8];
      #pragma unroll
      for (int mi=0;mi<2;mi++){
        int r = wr*32 + mi*16 + lr;
        af[mi] = *(const bf16x8*)&As4[r*8 + ((kk*4 + kb) ^ (r & 7))];
      }
      #pragma unroll
      for (int ni=0;ni<8;ni++){
        int r = wc*128 + ni*16 + lr;
        bfr[ni] = *(const bf16x8*)&Bs4[r*8 + ((kk*4 + kb) ^ (r & 7))];
      }
      #pragma unroll
      for (int mi=0;mi<2;mi++)
        #pragma unroll
        for (int ni=0;ni<8;ni++)
          acc[mi][ni] = __builtin_amdgcn_mfma_f32_16x16x32_bf16(af[mi], bfr[ni], acc[mi][ni], 0, 0, 0);
    }
    __syncthreads();
  }
  float p[2][4];
  #pragma unroll
  for (int mi=0;mi<2;mi++)
    #pragma unroll
    for (int r=0;r<4;r++) p[mi][r] = 0.f;
  #pragma unroll
  for (int mi=0;mi<2;mi++){
    #pragma unroll
    for (int ni=0;ni<8;ni++){
      int col = wc*128 + ni*16 + lr;
      #pragma unroll
      for (int r=0;r<4;r++){
        int row = wr*32 + mi*16 + kb*4 + r;
        float v = acc[mi][ni][r] + bf2f(residual[(size_t)(m0+row)*DM + col]);
        acc[mi][ni][r] = v;
        p[mi][r] += v*v;
      }
    }
  }
  #pragma unroll
  for (int mi=0;mi<2;mi++)
    #pragma unroll
    for (int r=0;r<4;r++){
      float s = p[mi][r];
      s += __shfl_xor(s, 1); s += __shfl_xor(s, 2);
      s += __shfl_xor(s, 4); s += __shfl_xor(s, 8);
      p[mi][r] = s;
    }
  if (lr == 0){
    #pragma unroll
    for (int mi=0;mi<2;mi++)
      #pragma unroll
      for (int r=0;r<4;r++)
        red[wr*32 + mi*16 + kb*4 + r][wc] = p[mi][r];
  }
  __syncthreads();
  #pragma unroll
  for (int mi=0;mi<2;mi++){
    float scm[4];
    #pragma unroll
    for (int r=0;r<4;r++){
      int row = wr*32 + mi*16 + kb*4 + r;
      scm[r] = rsqrtf((red[row][0]+red[row][1])*(1.f/DM) + 1e-4f);
    }
    #pragma unroll
    for (int ni=0;ni<8;ni++){
      int col = wc*128 + ni*16 + lr;
      float wn = WRITE_HS ? nw[col] : 0.f;
      #pragma unroll
      for (int r=0;r<4;r++){
        int row = wr*32 + mi*16 + kb*4 + r;
        float v = acc[mi][ni][r];
        residual[(size_t)(m0+row)*DM + col] = f2bf(v);
        if (WRITE_HS) hs[(size_t)(m0+row)*DM + col] = f2bf(v*scm[r]*wn);
      }
    }
  }
}

// ---------- 8-wave fc1 (N=256) + GLU fused ----------
__global__ __launch_bounds__(512) void k_fc1_glu(
    const u16* __restrict__ A, const u16* __restrict__ W, u16* __restrict__ out)
{
  const int K = DM;
  const int m0 = blockIdx.x * 128;
  const int tid = threadIdx.x;
  const int wv = tid >> 6, t = tid & 63;
  const int wr = wv >> 1, wc = wv & 1;
  const int lr = t & 15, kb = t >> 4;
  __shared__ uint4 As4[128*8];
  __shared__ uint4 Bs4[256*8];
  f32x4 acc[2][8];
  #pragma unroll
  for (int i=0;i<2;i++)
    #pragma unroll
    for (int j=0;j<8;j++) acc[i][j] = (f32x4){0.f,0.f,0.f,0.f};
  const int lr8 = t >> 3, lc8 = t & 7;
  const int sc  = lc8 ^ lr8;
  for (int k0 = 0; k0 < K; k0 += 64){
    #pragma unroll
    for (int i=0;i<2;i++){
      int r = i*64 + wv*8 + lr8;
      gl_lds16(A + (size_t)(m0 + r)*K + k0 + sc*8, &As4[(i*64 + wv*8)*8]);
    }
    #pragma unroll
    for (int i=0;i<4;i++){
      int r = i*64 + wv*8 + lr8;
      gl_lds16(W + (size_t)r*K + k0 + sc*8, &Bs4[(i*64 + wv*8)*8]);
    }
    __syncthreads();
    #pragma unroll
    for (int kk=0;kk<2;kk++){
      bf16x8 af[2], bfr[8];
      #pragma unroll
      for (int mi=0;mi<2;mi++){
        int r = wr*32 + mi*16 + lr;
        af[mi] = *(const bf16x8*)&As4[r*8 + ((kk*4 + kb) ^ (r & 7))];
      }
      #pragma unroll
      for (int ni=0;ni<8;ni++){
        int r = (ni < 4) ? (wc*64 + ni*16 + lr) : (128 + wc*64 + (ni-4)*16 + lr);
        bfr[ni] = *(const bf16x8*)&Bs4[r*8 + ((kk*4 + kb) ^ (r & 7))];
      }
      #pragma unroll
      for (int mi=0;mi<2;mi++)
        #pragma unroll
        for (int ni=0;ni<8;ni++)
          acc[mi][ni] = __builtin_amdgcn_mfma_f32_16x16x32_bf16(af[mi], bfr[ni], acc[mi][ni], 0, 0, 0);
    }
    __syncthreads();
  }
  #pragma unroll
  for (int mi=0;mi<2;mi++){
    #pragma unroll
    for (int ni=0;ni<4;ni++){
      int jcol = wc*64 + ni*16 + lr;
      #pragma unroll
      for (int r=0;r<4;r++){
        int row = wr*32 + mi*16 + kb*4 + r;
        float y = acc[mi][ni][r];
        float g = acc[mi][ni+4][r];
        out[(size_t)(m0+row)*MLPH + jcol] = f2bf(y * f_silu(g));
      }
    }
  }
}

// ---------- causal depthwise conv1d (k=4) + silu, 8-wide vectorized ----------
__global__ __launch_bounds__(256) void k_conv1d_silu(
    const u16* __restrict__ xz, const float* __restrict__ cw,
    const float* __restrict__ cb, u16* __restrict__ xcb)
{
  const int idx = blockIdx.x*256 + threadIdx.x;   // over Mc*64
  const int d0 = (idx & 63) * 8;
  const int m  = idx >> 6;
  const int l  = m & (L_SEQ-1);
  float acc[8];
  #pragma unroll
  for (int j=0;j<8;j++) acc[j] = cb[d0+j];
  float4 wv[8];
  #pragma unroll
  for (int j=0;j<8;j++) wv[j] = *(const float4*)(cw + (d0+j)*4);
  #pragma unroll
  for (int t=0;t<4;t++){
    if (l >= 3-t){
      bf16x8 v = *(const bf16x8*)(xz + (size_t)(m-3+t)*1024 + d0);
      #pragma unroll
      for (int j=0;j<8;j++){
        float wj = (t==0)?wv[j].x:(t==1)?wv[j].y:(t==2)?wv[j].z:wv[j].w;
        acc[j] += wj * bf2f((u16)v[j]);
      }
    }
  }
  u16 o[8];
  #pragma unroll
  for (int j=0;j<8;j++) o[j] = f2bf(f_silu(acc[j]));
  *(uint4*)(xcb + (size_t)m*DI + d0) = *(uint4*)o;
}

// ---------- chunked selective scan v6: packed-f32 (v_pk_fma) math ----------
__global__ __launch_bounds__(512) void k_scan6(
    const float* __restrict__ xdbl, const u16* __restrict__ xcb,
    const u16* __restrict__ xz, u16* __restrict__ ybf,
    const float* __restrict__ A_log, const float* __restrict__ Dp,
    const float* __restrict__ dtw, const float* __restrict__ dtb)
{
  const int b = blockIdx.x;
  const int lane = threadIdx.x & 63;
  const int w = threadIdx.x >> 6;          // chunk index 0..7
  const int d = blockIdx.y*64 + lane;
  __shared__ __align__(16) float BD[L_SEQ][48];   // 48 KB
  __shared__ u32 HT2[8][8][64];                   // 16 KB, packed bf16 h-pairs
  __shared__ float SD[8][64];                     // 2 KB
  const size_t rowbase = (size_t)b*L_SEQ;
  {
    const float4* src = (const float4*)(xdbl + rowbase*48);
    float4* dst = (float4*)&BD[0][0];
    #pragma unroll
    for (int j=0;j<6;j++) dst[threadIdx.x + j*512] = src[threadIdx.x + j*512];
  }
  f32x2 w2[8];
  #pragma unroll
  for (int k=0;k<8;k++){
    w2[k].x = dtw[(size_t)d*16 + 2*k];
    w2[k].y = dtw[(size_t)d*16 + 2*k + 1];
  }
  const float dtb_r = dtb[d];
  bool structured = true;
  #pragma unroll
  for (int n=0;n<16;n++){
    float Ar = -__expf(A_log[(size_t)d*16 + n]);
    structured = structured && (fabsf(Ar + (float)(n+1)) < 1e-4f*(float)(n+1));
  }
  const float Dv = Dp[d];
  const int l0 = w*32;
  float u_cur[8], z_cur[8];
  #pragma unroll
  for (int s=0;s<8;s++){
    u_cur[s] = bf2f(xcb[(rowbase+l0+s)*DI + d]);
    z_cur[s] = bf2f(xz [(rowbase+l0+s)*1024 + 512 + d]);
  }
  __syncthreads();
  // ---- phase A: local scan, h0 = 0 ----
  f32x2 h2[8];
  #pragma unroll
  for (int i=0;i<8;i++) h2[i] = (f32x2){0.f,0.f};
  float cum = 0.f;
  #pragma unroll
  for (int t8=0; t8<4; ++t8){
    float u_nxt[8], z_nxt[8];
    if (t8 < 3){
      #pragma unroll
      for (int s=0;s<8;s++){
        u_nxt[s] = bf2f(xcb[(rowbase+l0+t8*8+8+s)*DI + d]);
        z_nxt[s] = bf2f(xz [(rowbase+l0+t8*8+8+s)*1024 + 512 + d]);
      }
    }
    #pragma unroll
    for (int s=0;s<8;s++){
      const int l = l0 + t8*8 + s;
      const float u_v = u_cur[s], z_v = z_cur[s];
      const float4* bd4 = (const float4*)&BD[l][0];
      float4 X[4], Bq[4], Cq[4];
      #pragma unroll
      for (int j=0;j<4;j++){ X[j]=bd4[j]; Bq[j]=bd4[4+j]; Cq[j]=bd4[8+j]; }
      f32x2 xp[8], bp[8], cp[8];
      #pragma unroll
      for (int j=0;j<4;j++){
        xp[2*j]   = (f32x2){X[j].x,  X[j].y};  xp[2*j+1] = (f32x2){X[j].z,  X[j].w};
        bp[2*j]   = (f32x2){Bq[j].x, Bq[j].y}; bp[2*j+1] = (f32x2){Bq[j].z, Bq[j].w};
        cp[2*j]   = (f32x2){Cq[j].x, Cq[j].y}; cp[2*j+1] = (f32x2){Cq[j].z, Cq[j].w};
      }
      f32x2 a2 = xp[0]*w2[0], a2b = xp[1]*w2[1];
      #pragma unroll
      for (int j=2;j<8;j+=2){ a2 += xp[j]*w2[j]; a2b += xp[j+1]*w2[j+1]; }
      const float xr = dtb_r + (a2.x + a2.y) + (a2b.x + a2b.y);
      const float ex = __expf(xr);
      const float dt_v = (xr > 20.f) ? xr : __logf(1.f + ex);
      cum += dt_v;
      const f32x2 dtu2 = (f32x2){dt_v*u_v, dt_v*u_v};
      f32x2 y2 = (f32x2){0.f,0.f}, y2b = (f32x2){0.f,0.f};
      if (structured){
        const float p = 1.f/(1.f + ex);     // exp(-softplus(xr))
        f32x2 pw = (f32x2){p, p*p};
        const f32x2 e2 = (f32x2){pw.y, pw.y};
        #pragma unroll
        for (int i=0;i<8;i++){
          h2[i] = pw*h2[i] + dtu2*bp[i];
          if (i&1) y2b += h2[i]*cp[i]; else y2 += h2[i]*cp[i];
          if (i<7) pw = pw*e2;
        }
      } else {
        #pragma unroll
        for (int i=0;i<8;i++){
          float Ar0 = -__expf(A_log[(size_t)d*16 + 2*i]);
          float Ar1 = -__expf(A_log[(size_t)d*16 + 2*i+1]);
          f32x2 dA = (f32x2){__expf(dt_v*Ar0), __expf(dt_v*Ar1)};
          h2[i] = dA*h2[i] + dtu2*bp[i];
          if (i&1) y2b += h2[i]*cp[i]; else y2 += h2[i]*cp[i];
        }
      }
      const float y = (y2.x + y2.y) + (y2b.x + y2b.y);
      const float sz = f_silu(z_v);
      ybf[(rowbase+l)*DI + d] = f2bf((y + u_v*Dv) * sz);
    }
    if (t8 < 3){
      #pragma unroll
      for (int s=0;s<8;s++){ u_cur[s]=u_nxt[s]; z_cur[s]=z_nxt[s]; }
    }
  }
  SD[w][lane] = cum;
  #pragma unroll
  for (int i=0;i<8;i++)
    HT2[w][i][lane] = (u32)f2bf(h2[i].x) | ((u32)f2bf(h2[i].y) << 16);
  __syncthreads();
  if (w == 0) return;
  // ---- phase B ----
  f32x2 H02[8];
  #pragma unroll
  for (int i=0;i<8;i++) H02[i] = (f32x2){0.f,0.f};
  for (int c=0; c<w; ++c){
    float sdt = SD[c][lane];
    if (structured){
      float q = __expf(-sdt);
      f32x2 qw = (f32x2){q, q*q};
      const f32x2 e2 = (f32x2){qw.y, qw.y};
      #pragma unroll
      for (int i=0;i<8;i++){
        H02[i] = H02[i]*qw + unpk2(HT2[c][i][lane]);
        if (i<7) qw = qw*e2;
      }
    } else {
      #pragma unroll
      for (int i=0;i<8;i++){
        float Ar0 = -__expf(A_log[(size_t)d*16 + 2*i]);
        float Ar1 = -__expf(A_log[(size_t)d*16 + 2*i+1]);
        f32x2 dA = (f32x2){__expf(Ar0*sdt), __expf(Ar1*sdt)};
        H02[i] = H02[i]*dA + unpk2(HT2[c][i][lane]);
      }
    }
  }
  // ---- phase C ----
  float q = 1.f;
  float cum2 = 0.f;
  #pragma unroll
  for (int s=0;s<8;s++)
    z_cur[s] = bf2f(xz[(rowbase+l0+s)*1024 + 512 + d]);
  #pragma unroll
  for (int t8=0; t8<4; ++t8){
    float z_nxt[8];
    if (t8 < 3){
      #pragma unroll
      for (int s=0;s<8;s++)
        z_nxt[s] = bf2f(xz[(rowbase+l0+t8*8+8+s)*1024 + 512 + d]);
    }
    #pragma unroll
    for (int s=0;s<8;s++){
      const int l = l0 + t8*8 + s;
      const float4* bd4 = (const float4*)&BD[l][0];
      float4 X[4], Cq[4];
      #pragma unroll
      for (int j=0;j<4;j++){ X[j]=bd4[j]; Cq[j]=bd4[8+j]; }
      f32x2 xp[8], cp[8];
      #pragma unroll
      for (int j=0;j<4;j++){
        xp[2*j]   = (f32x2){X[j].x,  X[j].y};  xp[2*j+1] = (f32x2){X[j].z,  X[j].w};
        cp[2*j]   = (f32x2){Cq[j].x, Cq[j].y}; cp[2*j+1] = (f32x2){Cq[j].z, Cq[j].w};
      }
      f32x2 a2 = xp[0]*w2[0], a2b = xp[1]*w2[1];
      #pragma unroll
      for (int j=2;j<8;j+=2){ a2 += xp[j]*w2[j]; a2b += xp[j+1]*w2[j+1]; }
      const float xr = dtb_r + (a2.x + a2.y) + (a2b.x + a2b.y);
      const float ex = __expf(xr);
      f32x2 cacc = (f32x2){0.f,0.f}, caccb = (f32x2){0.f,0.f};
      if (structured){
        const float p = 1.f/(1.f + ex);
        q *= p;
        f32x2 qw = (f32x2){q, q*q};
        const f32x2 e2 = (f32x2){qw.y, qw.y};
        #pragma unroll
        for (int i=0;i<8;i++){
          f32x2 t = (cp[i]*H02[i])*qw;
          if (i&1) caccb += t; else cacc += t;
          if (i<7) qw = qw*e2;
        }
      } else {
        const float dt_v = (xr > 20.f) ? xr : __logf(1.f + ex);
        cum2 += dt_v;
        #pragma unroll
        for (int i=0;i<8;i++){
          float Ar0 = -__expf(A_log[(size_t)d*16 + 2*i]);
          float Ar1 = -__expf(A_log[(size_t)d*16 + 2*i+1]);
          f32x2 dA = (f32x2){__expf(Ar0*cum2), __expf(Ar1*cum2)};
          f32x2 t = (cp[i]*H02[i])*dA;
          if (i&1) caccb += t; else cacc += t;
        }
      }
      const float corr = (cacc.x + cacc.y) + (caccb.x + caccb.y);
      const float sz = f_silu(z_cur[s]);
      const size_t off = (rowbase+l)*DI + d;
      float prev = bf2f(ybf[off]);
      ybf[off] = f2bf(prev + corr*sz);
    }
    if (t8 < 3){
      #pragma unroll
      for (int s=0;s<8;s++) z_cur[s] = z_nxt[s];
    }
  }
}

// ---------- masked mean pool ----------
__global__ __launch_bounds__(256) void k_pool(
    const float* __restrict__ zf, const int* __restrict__ mask,
    float* __restrict__ pool, int b0)
{
  const int b = blockIdx.x;
  const int d = threadIdx.x;
  __shared__ float mrow[L_SEQ];
  for (int l = d; l < L_SEQ; l += 256) mrow[l] = (float)mask[(size_t)(b0+b)*L_SEQ + l];
  __syncthreads();
  float s = 0.f, ms = 0.f;
  for (int l=0;l<L_SEQ;l++){
    float mv = mrow[l];
    s  += mv * zf[((size_t)b*L_SEQ + l)*DM + d];
    ms += mv;
  }
  pool[(size_t)(b0+b)*DM + d] = s/ms;
}

// ---------- bind head ----------
__global__ __launch_bounds__(64) void k_bind(
    const float* __restrict__ pool, const float* __restrict__ bw,
    const float* __restrict__ bb, float* __restrict__ out)
{
  const int b = blockIdx.x;
  const int lane = threadIdx.x;
  float4 p = ((const float4*)(pool + (size_t)b*DM))[lane];
  #pragma unroll
  for (int j=0;j<3;j++){
    float4 w = ((const float4*)(bw + (size_t)j*DM))[lane];
    float s = p.x*w.x + p.y*w.y + p.z*w.z + p.w*w.w;
    #pragma unroll
    for (int m=1;m<64;m<<=1) s += __shfl_xor(s, m);
    if (lane==0) out[b*3 + j] = f_sigmoid(s + bb[j]);
  }
}

extern "C" void kernel_launch(void* const* d_in, const int* in_sizes, int n_in,
                              void* d_out, int out_size, void* d_ws, size_t ws_size,
                              hipStream_t stream)
{
  const int*   tok       = (const int*)  d_in[0];
  const int*   mask      = (const int*)  d_in[1];
  const float* emb       = (const float*)d_in[2];
  const float* conv_w    = (const float*)d_in[3];
  const float* bn_gamma  = (const float*)d_in[4];
  const float* bn_beta   = (const float*)d_in[5];
  const float* in_proj_w = (const float*)d_in[6];
  const float* conv1d_w  = (const float*)d_in[7];
  const float* conv1d_b  = (const float*)d_in[8];
  const float* x_proj_w  = (const float*)d_in[9];
  const float* dt_proj_w = (const float*)d_in[10];
  const float* dt_proj_b = (const float*)d_in[11];
  const float* A_log     = (const float*)d_in[12];
  const float* Dp        = (const float*)d_in[13];
  const float* out_proj_w= (const float*)d_in[14];
  const float* norm1_w   = (const float*)d_in[15];
  const float* norm2_w   = (const float*)d_in[16];
  const float* fc1_w     = (const float*)d_in[17];
  const float* fc2_w     = (const float*)d_in[18];
  const float* normf_w   = (const float*)d_in[19];
  const float* normf_b   = (const float*)d_in[20];
  const float* bind_w    = (const float*)d_in[21];
  const float* bind_b    = (const float*)d_in[22];
  float* outp = (float*)d_out;

  char* base = (char*)d_ws;
  size_t off = 0;
  const int NIN = NL*2*DI*DM, NOUT = NL*DM*DI, NF1 = NL*2*MLPH*DM, NF2 = NL*DM*MLPH, NXP = NL*64*DI;
  u16* w_in  = (u16*)(base + off); off += (size_t)NIN*2;
  u16* w_out = (u16*)(base + off); off += (size_t)NOUT*2;
  u16* w_f1  = (u16*)(base + off); off += (size_t)NF1*2;
  u16* w_f2  = (u16*)(base + off); off += (size_t)NF2*2;
  u16* w_xp  = (u16*)(base + off); off += (size_t)NXP*2;
  float* pool = (float*)(base + off); off += (size_t)B_TOT*DM*4;
  const size_t fixed = off;

  const size_t perRow = 48*4 + (256+1024+512+512+256+128)*2;
  int Bc = B_TOT;
  while (Bc > 1 && fixed + (size_t)Bc*L_SEQ*perRow > ws_size) Bc >>= 1;
  const int Mc = Bc * L_SEQ;

  u16*   residual = (u16*)(base + off);   off += (size_t)Mc*DM*2;
  float* xdbl     = (float*)(base + off); off += (size_t)Mc*48*4;
  u16*   xz       = (u16*)(base + off);   off += (size_t)Mc*1024*2;
  u16*   xcb      = (u16*)(base + off);   off += (size_t)Mc*DI*2;
  u16*   ybf      = (u16*)(base + off);   off += (size_t)Mc*DI*2;
  u16*   hsbf     = (u16*)(base + off);   off += (size_t)Mc*DM*2;
  u16*   glubf    = (u16*)(base + off);   off += (size_t)Mc*MLPH*2;
  float* zf       = (float*)xz;

  const int NCVT = NIN + NOUT + NF1 + NF2;
  k_cvt4<<<(NCVT+255)/256, 256, 0, stream>>>(in_proj_w, NIN, out_proj_w, NOUT,
                                             fc1_w, NF1, fc2_w, NF2, w_in);
  k_cvt_xproj<<<(NXP+255)/256, 256, 0, stream>>>(x_proj_w, w_xp);

  const int nmb = Mc/128;
  const bool canSwiz = (nmb & 7) == 0;
  const int nchunks = B_TOT / Bc;
  for (int c = 0; c < nchunks; ++c){
    const int b0 = c * Bc;
    k_embed_conv<<<dim3(L_SEQ/16, Bc), 256, 0, stream>>>(
        tok + (size_t)b0*L_SEQ, emb, conv_w, bn_gamma, bn_beta, residual);
    k_rms_first<<<Mc/4, 256, 0, stream>>>(residual, norm1_w, hsbf);

    for (int i = 0; i < NL; ++i){
      const u16*  inw  = w_in  + (size_t)i*(2*DI)*DM;
      const float* cw  = conv1d_w  + (size_t)i*DI*4;
      const float* cb  = conv1d_b  + (size_t)i*DI;
      const u16*  xpw  = w_xp  + (size_t)i*64*DI;
      const float* dtw = dt_proj_w + (size_t)i*DI*16;
      const float* dtb = dt_proj_b + (size_t)i*DI;
      const float* Alg = A_log     + (size_t)i*DI*DS;
      const float* Dpt = Dp        + (size_t)i*DI;
      const u16*  outw = w_out + (size_t)i*DM*DI;
      const float* n2w = norm2_w   + (size_t)i*DM;
      const u16*  f1w  = w_f1  + (size_t)i*(2*MLPH)*DM;
      const u16*  f2w  = w_f2  + (size_t)i*DM*MLPH;

      if (canSwiz)
        k_gemm_bf<128,true,true ><<<dim3(8*nmb), 256, 0, stream>>>(hsbf, inw, xz, 2*DI, DM, nmb);
      else
        k_gemm_bf<128,true,false><<<dim3(8, nmb), 256, 0, stream>>>(hsbf, inw, xz, 2*DI, DM, nmb);
      k_conv1d_silu<<<(Mc*64)/256, 256, 0, stream>>>(xz, cw, cb, xcb);
      k_gemm_bf<64, false,false><<<dim3(1, nmb), 256, 0, stream>>>(xcb, xpw, xdbl, 48, DI, nmb);
      k_scan6<<<dim3(Bc, 8), 512, 0, stream>>>(xdbl, xcb, xz, ybf, Alg, Dpt, dtw, dtb);
      k_gemm_rms<true><<<Mc/128, 512, 0, stream>>>(ybf, outw, residual, n2w, hsbf, DI);
      k_fc1_glu<<<Mc/128, 512, 0, stream>>>(hsbf, f1w, glubf);
      if (i < NL-1)
        k_gemm_rms<true ><<<Mc/128, 512, 0, stream>>>(glubf, f2w, residual,
                                                      norm1_w + (size_t)(i+1)*DM, hsbf, MLPH);
      else
        k_gemm_rms<false><<<Mc/128, 512, 0, stream>>>(glubf, f2w, residual,
                                                      nullptr, nullptr, MLPH);
    }

    k_final_ln<<<Mc/4, 256, 0, stream>>>(residual, normf_w, normf_b, zf);
    k_pool<<<Bc, 256, 0, stream>>>(zf, mask, pool, b0);
  }
  k_bind<<<B_TOT, 64, 0, stream>>>(pool, bind_w, bind_b, outp);
}

// Round 12
// 3651.408 us; speedup vs baseline: 1.0462x; 1.0462x over previous
//
#include <hip/hip_runtime.h>
#include <math.h>

#define B_TOT 256
#define L_SEQ 256
#define DM 256
#define DI 512
#define DS 16
#define NL 6
#define MLPH 128
#define ED 64

typedef unsigned short u16;
typedef unsigned int   u32;
using bf16x8 = __attribute__((ext_vector_type(8))) short;
using f32x4  = __attribute__((ext_vector_type(4))) float;
using f32x2  = __attribute__((ext_vector_type(2))) float;

__device__ __forceinline__ float f_sigmoid(float x){ return 1.f/(1.f+__expf(-x)); }
__device__ __forceinline__ float f_silu(float x){ return x/(1.f+__expf(-x)); }
__device__ __forceinline__ u16 f2bf(float x){
  union { float f; u32 u; } v; v.f = x;
  u32 r = v.u + 0x7fffu + ((v.u >> 16) & 1u);
  return (u16)(r >> 16);
}
__device__ __forceinline__ float bf2f(u16 h){
  union { u32 u; float f; } v; v.u = ((u32)h) << 16; return v.f;
}
__device__ __forceinline__ f32x2 unpk2(u32 v){
  union { u32 u; float f; } a, b;
  a.u = (v & 0xffffu) << 16; b.u = v & 0xffff0000u;
  f32x2 r; r.x = a.f; r.y = b.f; return r;
}

// ---------- weight conversion: 4 arrays in one launch ----------
__global__ __launch_bounds__(256) void k_cvt4(
    const float* __restrict__ s0, int n0, const float* __restrict__ s1, int n1,
    const float* __restrict__ s2, int n2, const float* __restrict__ s3, int n3,
    u16* __restrict__ d)
{
  int i = blockIdx.x*256 + threadIdx.x;
  float v;
  if (i < n0) v = s0[i];
  else if (i < n0+n1) v = s1[i-n0];
  else if (i < n0+n1+n2) v = s2[i-n0-n1];
  else if (i < n0+n1+n2+n3) v = s3[i-n0-n1-n2];
  else return;
  d[i] = f2bf(v);
}
__global__ __launch_bounds__(256) void k_cvt_xproj(const float* __restrict__ s, u16* __restrict__ d){
  int i = blockIdx.x*256 + threadIdx.x;      // over NL*64*512
  int k = i & 511; int n = (i>>9) & 63; int l = i >> 15;
  d[i] = (n < 48) ? f2bf(s[((size_t)l*48 + n)*512 + k]) : (u16)0;
}

// ---------- embedding + conv(k=3) + affine + relu -> residual (bf16) ----------
__global__ __launch_bounds__(256) void k_embed_conv(
    const int* __restrict__ tok, const float* __restrict__ emb,
    const float* __restrict__ cw, const float* __restrict__ gamma,
    const float* __restrict__ beta, u16* __restrict__ out)
{
  const int b  = blockIdx.y;
  const int lt = blockIdx.x;
  const int tid = threadIdx.x;
  __shared__ float xs[18][ED];
  for (int idx = tid; idx < 18*ED; idx += 256){
    int t = idx / ED, i = idx - t*ED;
    int l = lt*16 + t - 1;
    float v = 0.f;
    if (l >= 0 && l < L_SEQ) v = emb[tok[b*L_SEQ + l]*ED + i];
    xs[t][i] = v;
  }
  __syncthreads();
  const float g  = gamma[tid] * rsqrtf(1.001f);
  const float bt = beta[tid];
  const float* w = cw + (size_t)tid*(ED*3);
  float acc[16];
  #pragma unroll
  for (int t=0;t<16;t++) acc[t]=0.f;
  for (int i=0;i<ED;i++){
    float w0 = w[i*3+0], w1 = w[i*3+1], w2 = w[i*3+2];
    #pragma unroll
    for (int t=0;t<16;t++)
      acc[t] += xs[t][i]*w0 + xs[t+1][i]*w1 + xs[t+2][i]*w2;
  }
  #pragma unroll
  for (int t=0;t<16;t++){
    float v = acc[t]*g + bt;
    out[((size_t)(b*L_SEQ + lt*16 + t))*DM + tid] = f2bf(fmaxf(v, 0.f));
  }
}

// ---------- rmsnorm of residual (bf16) -> bf16 (first layer only) ----------
__global__ __launch_bounds__(256) void k_rms_first(
    const u16* __restrict__ residual, const float* __restrict__ w, u16* __restrict__ out)
{
  const int row  = blockIdx.x*4 + (threadIdx.x >> 6);
  const int lane = threadIdx.x & 63;
  const size_t base = (size_t)row*DM;
  uint2 rv = *(const uint2*)(residual + base + lane*4);
  float v0 = bf2f((u16)(rv.x & 0xffff)), v1 = bf2f((u16)(rv.x >> 16));
  float v2 = bf2f((u16)(rv.y & 0xffff)), v3 = bf2f((u16)(rv.y >> 16));
  float ss = v0*v0 + v1*v1 + v2*v2 + v3*v3;
  #pragma unroll
  for (int m=1; m<64; m<<=1) ss += __shfl_xor(ss, m);
  const float sc = rsqrtf(ss*(1.f/DM) + 1e-4f);
  float4 wv = ((const float4*)w)[lane];
  u32 p0 = f2bf(v0*sc*wv.x) | ((u32)f2bf(v1*sc*wv.y) << 16);
  u32 p1 = f2bf(v2*sc*wv.z) | ((u32)f2bf(v3*sc*wv.w) << 16);
  uint2 pk; pk.x = p0; pk.y = p1;
  *(uint2*)(out + base + lane*4) = pk;
}

// ---------- final layernorm (residual bf16 in, f32 out) ----------
__global__ __launch_bounds__(256) void k_final_ln(
    const u16* __restrict__ x,
    const float* __restrict__ w, const float* __restrict__ bb, float* __restrict__ out)
{
  const int row  = blockIdx.x*4 + (threadIdx.x >> 6);
  const int lane = threadIdx.x & 63;
  const size_t base = (size_t)row*DM;
  uint2 rv = *(const uint2*)(x + base + lane*4);
  float4 v;
  v.x = bf2f((u16)(rv.x & 0xffff)); v.y = bf2f((u16)(rv.x >> 16));
  v.z = bf2f((u16)(rv.y & 0xffff)); v.w = bf2f((u16)(rv.y >> 16));
  float s = v.x + v.y + v.z + v.w;
  #pragma unroll
  for (int m=1; m<64; m<<=1) s += __shfl_xor(s, m);
  const float mu = s*(1.f/DM);
  float4 c; c.x=v.x-mu; c.y=v.y-mu; c.z=v.z-mu; c.w=v.w-mu;
  float ss = c.x*c.x + c.y*c.y + c.z*c.z + c.w*c.w;
  #pragma unroll
  for (int m=1; m<64; m<<=1) ss += __shfl_xor(ss, m);
  const float sc = rsqrtf(ss*(1.f/DM) + 1e-4f);
  float4 wv = ((const float4*)w)[lane];
  float4 bv = ((const float4*)bb)[lane];
  float4 o;
  o.x = c.x*sc*wv.x + bv.x; o.y = c.y*sc*wv.y + bv.y;
  o.z = c.z*sc*wv.z + bv.z; o.w = c.w*sc*wv.w + bv.w;
  ((float4*)(out + base))[lane] = o;
}

// ---------- bf16 MFMA GEMM (4 waves, reg-staged) ----------
template<int BN, bool BF16OUT, bool SWIZ>
__global__ __launch_bounds__(256) void k_gemm_bf(
    const u16* __restrict__ A, const u16* __restrict__ W,
    void* __restrict__ Cv, int Nc, int K, int nmb)
{
  int bx, by;
  if (SWIZ){
    const int id = blockIdx.x;
    const int xcd = id & 7, rem = id >> 3;
    const int per = nmb >> 3;
    by = xcd*per + (rem % per);
    bx = rem / per;
  } else { bx = blockIdx.x; by = blockIdx.y; }
  const int n0 = bx * BN;
  const int m0 = by * 128;
  const int tid = threadIdx.x;
  const int w  = tid >> 6, l = tid & 63;
  const int wr = w >> 1, wc = w & 1;
  const int lr = l & 15, kb = l >> 4;
  constexpr int NJ = BN / 32;
  __shared__ uint4 As4[128*8];
  __shared__ uint4 Bs4[BN*8];
  f32x4 acc[4][NJ];
  #pragma unroll
  for (int i=0;i<4;i++)
    #pragma unroll
    for (int j=0;j<NJ;j++)
      acc[i][j] = (f32x4){0.f,0.f,0.f,0.f};
  const int srow = tid >> 3, schunk = tid & 7;
  for (int k0 = 0; k0 < K; k0 += 64){
    #pragma unroll
    for (int i=0;i<4;i++){
      int r = i*32 + srow;
      uint4 v = *(const uint4*)(A + (size_t)(m0 + r)*K + k0 + schunk*8);
      As4[r*8 + (schunk ^ (r & 7))] = v;
    }
    #pragma unroll
    for (int i=0;i<BN/32;i++){
      int r = i*32 + srow;
      uint4 v = *(const uint4*)(W + (size_t)(n0 + r)*K + k0 + schunk*8);
      Bs4[r*8 + (schunk ^ (r & 7))] = v;
    }
    __syncthreads();
    #pragma unroll
    for (int kk=0;kk<2;kk++){
      bf16x8 af[4], bfr[NJ];
      #pragma unroll
      for (int mi=0;mi<4;mi++){
        int r = wr*64 + mi*16 + lr;
        af[mi] = *(const bf16x8*)&As4[r*8 + ((kk*4 + kb) ^ (r & 7))];
      }
      #pragma unroll
      for (int ni=0;ni<NJ;ni++){
        int r = wc*(BN/2) + ni*16 + lr;
        bfr[ni] = *(const bf16x8*)&Bs4[r*8 + ((kk*4 + kb) ^ (r & 7))];
      }
      #pragma unroll
      for (int mi=0;mi<4;mi++)
        #pragma unroll
        for (int ni=0;ni<NJ;ni++)
          acc[mi][ni] = __builtin_amdgcn_mfma_f32_16x16x32_bf16(af[mi], bfr[ni], acc[mi][ni], 0, 0, 0);
    }
    __syncthreads();
  }
  #pragma unroll
  for (int mi=0;mi<4;mi++){
    #pragma unroll
    for (int ni=0;ni<NJ;ni++){
      int col = n0 + wc*(BN/2) + ni*16 + lr;
      if (col < Nc){
        #pragma unroll
        for (int r=0;r<4;r++){
          size_t row = (size_t)(m0 + wr*64 + mi*16 + kb*4 + r);
          if (BF16OUT) ((u16*)Cv)[row*Nc + col] = f2bf(acc[mi][ni][r]);
          else         ((float*)Cv)[row*Nc + col] = acc[mi][ni][r];
        }
      }
    }
  }
}

// ---------- 8-wave GEMM (N=256) + residual(bf16) add + rmsnorm fused ----------
template<bool WRITE_HS>
__global__ __launch_bounds__(512) void k_gemm_rms(
    const u16* __restrict__ A, const u16* __restrict__ W,
    u16* __restrict__ residual, const float* __restrict__ nw,
    u16* __restrict__ hs, int K)
{
  const int m0 = blockIdx.x * 128;
  const int tid = threadIdx.x;
  const int w = tid >> 6, l = tid & 63;
  const int wr = w >> 1, wc = w & 1;
  const int lr = l & 15, kb = l >> 4;
  __shared__ uint4 As4[128*8];
  __shared__ uint4 Bs4[256*8];
  __shared__ float red[128][2];
  f32x4 acc[2][8];
  #pragma unroll
  for (int i=0;i<2;i++)
    #pragma unroll
    for (int j=0;j<8;j++) acc[i][j] = (f32x4){0.f,0.f,0.f,0.f};
  const int srow = tid >> 3, schunk = tid & 7;
  for (int k0 = 0; k0 < K; k0 += 64){
    #pragma unroll
    for (int i=0;i<2;i++){
      int r = i*64 + srow;
      uint4 v = *(const uint4*)(A + (size_t)(m0 + r)*K + k0 + schunk*8);
      As4[r*8 + (schunk ^ (r & 7))] = v;
    }
    #pragma unroll
    for (int i=0;i<4;i++){
      int r = i*64 + srow;
      uint4 v = *(const uint4*)(W + (size_t)r*K + k0 + schunk*8);
      Bs4[r*8 + (schunk ^ (r & 7))] = v;
    }
    __syncthreads();
    #pragma unroll
    for (int kk=0;kk<2;kk++){
      bf16x8 af[2], bfr[8];
      #pragma unroll
      for (int mi=0;mi<2;mi++){
        int r = wr*32 + mi*16 + lr;
        af[mi] = *(const bf16x8*)&As4[r*8 + ((kk*4 + kb) ^ (r & 7))];
      }
      #pragma unroll
      for (int ni=0;ni<8;ni++){
        int r = wc*128 + ni*16 + lr;
        bfr[ni] = *(const bf16x8*)&Bs4[r*8 + ((kk*4 + kb) ^ (r & 7))];
      }
      #pragma unroll
      for (int mi=0;mi<2;mi++)
        #pragma unroll
        for (int ni=0;ni<8;ni++)
          acc[mi][ni] = __builtin_amdgcn_mfma_f32_16x16x32_bf16(af[mi], bfr[ni], acc[mi][ni], 0, 0, 0);
    }
    __syncthreads();
  }
  float p[2][4];
  #pragma unroll
  for (int mi=0;mi<2;mi++)
    #pragma unroll
    for (int r=0;r<4;r++) p[mi][r] = 0.f;
  #pragma unroll
  for (int mi=0;mi<2;mi++){
    #pragma unroll
    for (int ni=0;ni<8;ni++){
      int col = wc*128 + ni*16 + lr;
      #pragma unroll
      for (int r=0;r<4;r++){
        int row = wr*32 + mi*16 + kb*4 + r;
        float v = acc[mi][ni][r] + bf2f(residual[(size_t)(m0+row)*DM + col]);
        acc[mi][ni][r] = v;
        p[mi][r] += v*v;
      }
    }
  }
  #pragma unroll
  for (int mi=0;mi<2;mi++)
    #pragma unroll
    for (int r=0;r<4;r++){
      float s = p[mi][r];
      s += __shfl_xor(s, 1); s += __shfl_xor(s, 2);
      s += __shfl_xor(s, 4); s += __shfl_xor(s, 8);
      p[mi][r] = s;
    }
  if (lr == 0){
    #pragma unroll
    for (int mi=0;mi<2;mi++)
      #pragma unroll
      for (int r=0;r<4;r++)
        red[wr*32 + mi*16 + kb*4 + r][wc] = p[mi][r];
  }
  __syncthreads();
  #pragma unroll
  for (int mi=0;mi<2;mi++){
    float scm[4];
    #pragma unroll
    for (int r=0;r<4;r++){
      int row = wr*32 + mi*16 + kb*4 + r;
      scm[r] = rsqrtf((red[row][0]+red[row][1])*(1.f/DM) + 1e-4f);
    }
    #pragma unroll
    for (int ni=0;ni<8;ni++){
      int col = wc*128 + ni*16 + lr;
      float wn = WRITE_HS ? nw[col] : 0.f;
      #pragma unroll
      for (int r=0;r<4;r++){
        int row = wr*32 + mi*16 + kb*4 + r;
        float v = acc[mi][ni][r];
        residual[(size_t)(m0+row)*DM + col] = f2bf(v);
        if (WRITE_HS) hs[(size_t)(m0+row)*DM + col] = f2bf(v*scm[r]*wn);
      }
    }
  }
}

// ---------- 8-wave fc1 (N=256) + GLU fused ----------
__global__ __launch_bounds__(512) void k_fc1_glu(
    const u16* __restrict__ A, const u16* __restrict__ W, u16* __restrict__ out)
{
  const int K = DM;
  const int m0 = blockIdx.x * 128;
  const int tid = threadIdx.x;
  const int w = tid >> 6, l = tid & 63;
  const int wr = w >> 1, wc = w & 1;
  const int lr = l & 15, kb = l >> 4;
  __shared__ uint4 As4[128*8];
  __shared__ uint4 Bs4[256*8];
  f32x4 acc[2][8];
  #pragma unroll
  for (int i=0;i<2;i++)
    #pragma unroll
    for (int j=0;j<8;j++) acc[i][j] = (f32x4){0.f,0.f,0.f,0.f};
  const int srow = tid >> 3, schunk = tid & 7;
  for (int k0 = 0; k0 < K; k0 += 64){
    #pragma unroll
    for (int i=0;i<2;i++){
      int r = i*64 + srow;
      uint4 v = *(const uint4*)(A + (size_t)(m0 + r)*K + k0 + schunk*8);
      As4[r*8 + (schunk ^ (r & 7))] = v;
    }
    #pragma unroll
    for (int i=0;i<4;i++){
      int r = i*64 + srow;
      uint4 v = *(const uint4*)(W + (size_t)r*K + k0 + schunk*8);
      Bs4[r*8 + (schunk ^ (r & 7))] = v;
    }
    __syncthreads();
    #pragma unroll
    for (int kk=0;kk<2;kk++){
      bf16x8 af[2], bfr[8];
      #pragma unroll
      for (int mi=0;mi<2;mi++){
        int r = wr*32 + mi*16 + lr;
        af[mi] = *(const bf16x8*)&As4[r*8 + ((kk*4 + kb) ^ (r & 7))];
      }
      #pragma unroll
      for (int ni=0;ni<8;ni++){
        int r = (ni < 4) ? (wc*64 + ni*16 + lr) : (128 + wc*64 + (ni-4)*16 + lr);
        bfr[ni] = *(const bf16x8*)&Bs4[r*8 + ((kk*4 + kb) ^ (r & 7))];
      }
      #pragma unroll
      for (int mi=0;mi<2;mi++)
        #pragma unroll
        for (int ni=0;ni<8;ni++)
          acc[mi][ni] = __builtin_amdgcn_mfma_f32_16x16x32_bf16(af[mi], bfr[ni], acc[mi][ni], 0, 0, 0);
    }
    __syncthreads();
  }
  #pragma unroll
  for (int mi=0;mi<2;mi++){
    #pragma unroll
    for (int ni=0;ni<4;ni++){
      int jcol = wc*64 + ni*16 + lr;
      #pragma unroll
      for (int r=0;r<4;r++){
        int row = wr*32 + mi*16 + kb*4 + r;
        float y = acc[mi][ni][r];
        float g = acc[mi][ni+4][r];
        out[(size_t)(m0+row)*MLPH + jcol] = f2bf(y * f_silu(g));
      }
    }
  }
}

// ---------- causal depthwise conv1d (k=4) + silu, 8-wide vectorized ----------
__global__ __launch_bounds__(256) void k_conv1d_silu(
    const u16* __restrict__ xz, const float* __restrict__ cw,
    const float* __restrict__ cb, u16* __restrict__ xcb)
{
  const int idx = blockIdx.x*256 + threadIdx.x;   // over Mc*64
  const int d0 = (idx & 63) * 8;
  const int m  = idx >> 6;
  const int l  = m & (L_SEQ-1);
  float acc[8];
  #pragma unroll
  for (int j=0;j<8;j++) acc[j] = cb[d0+j];
  float4 wv[8];
  #pragma unroll
  for (int j=0;j<8;j++) wv[j] = *(const float4*)(cw + (d0+j)*4);
  #pragma unroll
  for (int t=0;t<4;t++){
    if (l >= 3-t){
      bf16x8 v = *(const bf16x8*)(xz + (size_t)(m-3+t)*1024 + d0);
      #pragma unroll
      for (int j=0;j<8;j++){
        float wj = (t==0)?wv[j].x:(t==1)?wv[j].y:(t==2)?wv[j].z:wv[j].w;
        acc[j] += wj * bf2f((u16)v[j]);
      }
    }
  }
  u16 o[8];
  #pragma unroll
  for (int j=0;j<8;j++) o[j] = f2bf(f_silu(acc[j]));
  *(uint4*)(xcb + (size_t)m*DI + d0) = *(uint4*)o;
}

// ---------- chunked selective scan v6: packed-f32 math (round-10 version) ----------
__global__ __launch_bounds__(512) void k_scan6(
    const float* __restrict__ xdbl, const u16* __restrict__ xcb,
    const u16* __restrict__ xz, u16* __restrict__ ybf,
    const float* __restrict__ A_log, const float* __restrict__ Dp,
    const float* __restrict__ dtw, const float* __restrict__ dtb)
{
  const int b = blockIdx.x;
  const int lane = threadIdx.x & 63;
  const int w = threadIdx.x >> 6;
  const int d = blockIdx.y*64 + lane;
  __shared__ __align__(16) float BD[L_SEQ][48];
  __shared__ u32 HT2[8][8][64];
  __shared__ float SD[8][64];
  const size_t rowbase = (size_t)b*L_SEQ;
  {
    const float4* src = (const float4*)(xdbl + rowbase*48);
    float4* dst = (float4*)&BD[0][0];
    #pragma unroll
    for (int j=0;j<6;j++) dst[threadIdx.x + j*512] = src[threadIdx.x + j*512];
  }
  f32x2 w2[8];
  #pragma unroll
  for (int k=0;k<8;k++){
    w2[k].x = dtw[(size_t)d*16 + 2*k];
    w2[k].y = dtw[(size_t)d*16 + 2*k + 1];
  }
  const float dtb_r = dtb[d];
  bool structured = true;
  #pragma unroll
  for (int n=0;n<16;n++){
    float Ar = -__expf(A_log[(size_t)d*16 + n]);
    structured = structured && (fabsf(Ar + (float)(n+1)) < 1e-4f*(float)(n+1));
  }
  const float Dv = Dp[d];
  const int l0 = w*32;
  float u_cur[8], z_cur[8];
  #pragma unroll
  for (int s=0;s<8;s++){
    u_cur[s] = bf2f(xcb[(rowbase+l0+s)*DI + d]);
    z_cur[s] = bf2f(xz [(rowbase+l0+s)*1024 + 512 + d]);
  }
  __syncthreads();
  f32x2 h2[8];
  #pragma unroll
  for (int i=0;i<8;i++) h2[i] = (f32x2){0.f,0.f};
  float cum = 0.f;
  #pragma unroll
  for (int t8=0; t8<4; ++t8){
    float u_nxt[8], z_nxt[8];
    if (t8 < 3){
      #pragma unroll
      for (int s=0;s<8;s++){
        u_nxt[s] = bf2f(xcb[(rowbase+l0+t8*8+8+s)*DI + d]);
        z_nxt[s] = bf2f(xz [(rowbase+l0+t8*8+8+s)*1024 + 512 + d]);
      }
    }
    #pragma unroll
    for (int s=0;s<8;s++){
      const int l = l0 + t8*8 + s;
      const float u_v = u_cur[s], z_v = z_cur[s];
      const float4* bd4 = (const float4*)&BD[l][0];
      float4 X[4], Bq[4], Cq[4];
      #pragma unroll
      for (int j=0;j<4;j++){ X[j]=bd4[j]; Bq[j]=bd4[4+j]; Cq[j]=bd4[8+j]; }
      f32x2 xp[8], bp[8], cp[8];
      #pragma unroll
      for (int j=0;j<4;j++){
        xp[2*j]   = (f32x2){X[j].x,  X[j].y};  xp[2*j+1] = (f32x2){X[j].z,  X[j].w};
        bp[2*j]   = (f32x2){Bq[j].x, Bq[j].y}; bp[2*j+1] = (f32x2){Bq[j].z, Bq[j].w};
        cp[2*j]   = (f32x2){Cq[j].x, Cq[j].y}; cp[2*j+1] = (f32x2){Cq[j].z, Cq[j].w};
      }
      f32x2 a2 = xp[0]*w2[0], a2b = xp[1]*w2[1];
      #pragma unroll
      for (int j=2;j<8;j+=2){ a2 += xp[j]*w2[j]; a2b += xp[j+1]*w2[j+1]; }
      const float xr = dtb_r + (a2.x + a2.y) + (a2b.x + a2b.y);
      const float ex = __expf(xr);
      const float dt_v = (xr > 20.f) ? xr : __logf(1.f + ex);
      cum += dt_v;
      const f32x2 dtu2 = (f32x2){dt_v*u_v, dt_v*u_v};
      f32x2 y2 = (f32x2){0.f,0.f}, y2b = (f32x2){0.f,0.f};
      if (structured){
        const float p = 1.f/(1.f + ex);
        f32x2 pw = (f32x2){p, p*p};
        const f32x2 e2 = (f32x2){pw.y, pw.y};
        #pragma unroll
        for (int i=0;i<8;i++){
          h2[i] = pw*h2[i] + dtu2*bp[i];
          if (i&1) y2b += h2[i]*cp[i]; else y2 += h2[i]*cp[i];
          if (i<7) pw = pw*e2;
        }
      } else {
        #pragma unroll
        for (int i=0;i<8;i++){
          float Ar0 = -__expf(A_log[(size_t)d*16 + 2*i]);
          float Ar1 = -__expf(A_log[(size_t)d*16 + 2*i+1]);
          f32x2 dA = (f32x2){__expf(dt_v*Ar0), __expf(dt_v*Ar1)};
          h2[i] = dA*h2[i] + dtu2*bp[i];
          if (i&1) y2b += h2[i]*cp[i]; else y2 += h2[i]*cp[i];
        }
      }
      const float y = (y2.x + y2.y) + (y2b.x + y2b.y);
      const float sz = f_silu(z_v);
      ybf[(rowbase+l)*DI + d] = f2bf((y + u_v*Dv) * sz);
    }
    if (t8 < 3){
      #pragma unroll
      for (int s=0;s<8;s++){ u_cur[s]=u_nxt[s]; z_cur[s]=z_nxt[s]; }
    }
  }
  SD[w][lane] = cum;
  #pragma unroll
  for (int i=0;i<8;i++)
    HT2[w][i][lane] = (u32)f2bf(h2[i].x) | ((u32)f2bf(h2[i].y) << 16);
  __syncthreads();
  if (w == 0) return;
  f32x2 H02[8];
  #pragma unroll
  for (int i=0;i<8;i++) H02[i] = (f32x2){0.f,0.f};
  for (int c=0; c<w; ++c){
    float sdt = SD[c][lane];
    if (structured){
      float q = __expf(-sdt);
      f32x2 qw = (f32x2){q, q*q};
      const f32x2 e2 = (f32x2){qw.y, qw.y};
      #pragma unroll
      for (int i=0;i<8;i++){
        H02[i] = H02[i]*qw + unpk2(HT2[c][i][lane]);
        if (i<7) qw = qw*e2;
      }
    } else {
      #pragma unroll
      for (int i=0;i<8;i++){
        float Ar0 = -__expf(A_log[(size_t)d*16 + 2*i]);
        float Ar1 = -__expf(A_log[(size_t)d*16 + 2*i+1]);
        f32x2 dA = (f32x2){__expf(Ar0*sdt), __expf(Ar1*sdt)};
        H02[i] = H02[i]*dA + unpk2(HT2[c][i][lane]);
      }
    }
  }
  float q = 1.f;
  float cum2 = 0.f;
  #pragma unroll
  for (int s=0;s<8;s++)
    z_cur[s] = bf2f(xz[(rowbase+l0+s)*1024 + 512 + d]);
  #pragma unroll
  for (int t8=0; t8<4; ++t8){
    float z_nxt[8];
    if (t8 < 3){
      #pragma unroll
      for (int s=0;s<8;s++)
        z_nxt[s] = bf2f(xz[(rowbase+l0+t8*8+8+s)*1024 + 512 + d]);
    }
    #pragma unroll
    for (int s=0;s<8;s++){
      const int l = l0 + t8*8 + s;
      const float4* bd4 = (const float4*)&BD[l][0];
      float4 X[4], Cq[4];
      #pragma unroll
      for (int j=0;j<4;j++){ X[j]=bd4[j]; Cq[j]=bd4[8+j]; }
      f32x2 xp[8], cp[8];
      #pragma unroll
      for (int j=0;j<4;j++){
        xp[2*j]   = (f32x2){X[j].x,  X[j].y};  xp[2*j+1] = (f32x2){X[j].z,  X[j].w};
        cp[2*j]   = (f32x2){Cq[j].x, Cq[j].y}; cp[2*j+1] = (f32x2){Cq[j].z, Cq[j].w};
      }
      f32x2 a2 = xp[0]*w2[0], a2b = xp[1]*w2[1];
      #pragma unroll
      for (int j=2;j<8;j+=2){ a2 += xp[j]*w2[j]; a2b += xp[j+1]*w2[j+1]; }
      const float xr = dtb_r + (a2.x + a2.y) + (a2b.x + a2b.y);
      const float ex = __expf(xr);
      f32x2 cacc = (f32x2){0.f,0.f}, caccb = (f32x2){0.f,0.f};
      if (structured){
        const float p = 1.f/(1.f + ex);
        q *= p;
        f32x2 qw = (f32x2){q, q*q};
        const f32x2 e2 = (f32x2){qw.y, qw.y};
        #pragma unroll
        for (int i=0;i<8;i++){
          f32x2 t = (cp[i]*H02[i])*qw;
          if (i&1) caccb += t; else cacc += t;
          if (i<7) qw = qw*e2;
        }
      } else {
        const float dt_v = (xr > 20.f) ? xr : __logf(1.f + ex);
        cum2 += dt_v;
        #pragma unroll
        for (int i=0;i<8;i++){
          float Ar0 = -__expf(A_log[(size_t)d*16 + 2*i]);
          float Ar1 = -__expf(A_log[(size_t)d*16 + 2*i+1]);
          f32x2 dA = (f32x2){__expf(Ar0*cum2), __expf(Ar1*cum2)};
          f32x2 t = (cp[i]*H02[i])*dA;
          if (i&1) caccb += t; else cacc += t;
        }
      }
      const float corr = (cacc.x + cacc.y) + (caccb.x + caccb.y);
      const float sz = f_silu(z_cur[s]);
      const size_t off = (rowbase+l)*DI + d;
      float prev = bf2f(ybf[off]);
      ybf[off] = f2bf(prev + corr*sz);
    }
    if (t8 < 3){
      #pragma unroll
      for (int s=0;s<8;s++) z_cur[s] = z_nxt[s];
    }
  }
}

// ---------- masked mean pool (1024 threads, 4 l-slices) ----------
__global__ __launch_bounds__(1024) void k_pool(
    const float* __restrict__ zf, const int* __restrict__ mask,
    float* __restrict__ pool, int b0)
{
  const int b = blockIdx.x;
  const int d = threadIdx.x & 255;
  const int lg = threadIdx.x >> 8;       // 0..3
  __shared__ float red[4][DM];
  __shared__ float msum[4];
  float s = 0.f, ms = 0.f;
  for (int l = lg*64; l < lg*64 + 64; ++l){
    float mv = (float)mask[(size_t)(b0+b)*L_SEQ + l];
    s  += mv * zf[((size_t)b*L_SEQ + l)*DM + d];
    ms += mv;
  }
  red[lg][d] = s;
  if (d == 0) msum[lg] = ms;
  __syncthreads();
  if (lg == 0){
    float tot = red[0][d] + red[1][d] + red[2][d] + red[3][d];
    float m = msum[0] + msum[1] + msum[2] + msum[3];
    pool[(size_t)(b0+b)*DM + d] = tot/m;
  }
}

// ---------- bind head ----------
__global__ __launch_bounds__(64) void k_bind(
    const float* __restrict__ pool, const float* __restrict__ bw,
    const float* __restrict__ bb, float* __restrict__ out)
{
  const int b = blockIdx.x;
  const int lane = threadIdx.x;
  float4 p = ((const float4*)(pool + (size_t)b*DM))[lane];
  #pragma unroll
  for (int j=0;j<3;j++){
    float4 w = ((const float4*)(bw + (size_t)j*DM))[lane];
    float s = p.x*w.x + p.y*w.y + p.z*w.z + p.w*w.w;
    #pragma unroll
    for (int m=1;m<64;m<<=1) s += __shfl_xor(s, m);
    if (lane==0) out[b*3 + j] = f_sigmoid(s + bb[j]);
  }
}

extern "C" void kernel_launch(void* const* d_in, const int* in_sizes, int n_in,
                              void* d_out, int out_size, void* d_ws, size_t ws_size,
                              hipStream_t stream)
{
  const int*   tok       = (const int*)  d_in[0];
  const int*   mask      = (const int*)  d_in[1];
  const float* emb       = (const float*)d_in[2];
  const float* conv_w    = (const float*)d_in[3];
  const float* bn_gamma  = (const float*)d_in[4];
  const float* bn_beta   = (const float*)d_in[5];
  const float* in_proj_w = (const float*)d_in[6];
  const float* conv1d_w  = (const float*)d_in[7];
  const float* conv1d_b  = (const float*)d_in[8];
  const float* x_proj_w  = (const float*)d_in[9];
  const float* dt_proj_w = (const float*)d_in[10];
  const float* dt_proj_b = (const float*)d_in[11];
  const float* A_log     = (const float*)d_in[12];
  const float* Dp        = (const float*)d_in[13];
  const float* out_proj_w= (const float*)d_in[14];
  const float* norm1_w   = (const float*)d_in[15];
  const float* norm2_w   = (const float*)d_in[16];
  const float* fc1_w     = (const float*)d_in[17];
  const float* fc2_w     = (const float*)d_in[18];
  const float* normf_w   = (const float*)d_in[19];
  const float* normf_b   = (const float*)d_in[20];
  const float* bind_w    = (const float*)d_in[21];
  const float* bind_b    = (const float*)d_in[22];
  float* outp = (float*)d_out;

  char* base = (char*)d_ws;
  size_t off = 0;
  const int NIN = NL*2*DI*DM, NOUT = NL*DM*DI, NF1 = NL*2*MLPH*DM, NF2 = NL*DM*MLPH, NXP = NL*64*DI;
  u16* w_in  = (u16*)(base + off); off += (size_t)NIN*2;
  u16* w_out = (u16*)(base + off); off += (size_t)NOUT*2;
  u16* w_f1  = (u16*)(base + off); off += (size_t)NF1*2;
  u16* w_f2  = (u16*)(base + off); off += (size_t)NF2*2;
  u16* w_xp  = (u16*)(base + off); off += (size_t)NXP*2;
  float* pool = (float*)(base + off); off += (size_t)B_TOT*DM*4;
  const size_t fixed = off;

  const size_t perRow = 48*4 + (256+1024+512+512+256+128)*2;
  int Bc = B_TOT;
  while (Bc > 1 && fixed + (size_t)Bc*L_SEQ*perRow > ws_size) Bc >>= 1;
  const int Mc = Bc * L_SEQ;

  u16*   residual = (u16*)(base + off);   off += (size_t)Mc*DM*2;
  float* xdbl     = (float*)(base + off); off += (size_t)Mc*48*4;
  u16*   xz       = (u16*)(base + off);   off += (size_t)Mc*1024*2;
  u16*   xcb      = (u16*)(base + off);   off += (size_t)Mc*DI*2;
  u16*   ybf      = (u16*)(base + off);   off += (size_t)Mc*DI*2;
  u16*   hsbf     = (u16*)(base + off);   off += (size_t)Mc*DM*2;
  u16*   glubf    = (u16*)(base + off);   off += (size_t)Mc*MLPH*2;
  float* zf       = (float*)xz;

  const int NCVT = NIN + NOUT + NF1 + NF2;
  k_cvt4<<<(NCVT+255)/256, 256, 0, stream>>>(in_proj_w, NIN, out_proj_w, NOUT,
                                             fc1_w, NF1, fc2_w, NF2, w_in);
  k_cvt_xproj<<<(NXP+255)/256, 256, 0, stream>>>(x_proj_w, w_xp);

  const int nmb = Mc/128;
  const bool canSwiz = (nmb & 7) == 0;
  const int nchunks = B_TOT / Bc;
  for (int c = 0; c < nchunks; ++c){
    const int b0 = c * Bc;
    k_embed_conv<<<dim3(L_SEQ/16, Bc), 256, 0, stream>>>(
        tok + (size_t)b0*L_SEQ, emb, conv_w, bn_gamma, bn_beta, residual);
    k_rms_first<<<Mc/4, 256, 0, stream>>>(residual, norm1_w, hsbf);

    for (int i = 0; i < NL; ++i){
      const u16*  inw  = w_in  + (size_t)i*(2*DI)*DM;
      const float* cw  = conv1d_w  + (size_t)i*DI*4;
      const float* cb  = conv1d_b  + (size_t)i*DI;
      const u16*  xpw  = w_xp  + (size_t)i*64*DI;
      const float* dtw = dt_proj_w + (size_t)i*DI*16;
      const float* dtb = dt_proj_b + (size_t)i*DI;
      const float* Alg = A_log     + (size_t)i*DI*DS;
      const float* Dpt = Dp        + (size_t)i*DI;
      const u16*  outw = w_out + (size_t)i*DM*DI;
      const float* n2w = norm2_w   + (size_t)i*DM;
      const u16*  f1w  = w_f1  + (size_t)i*(2*MLPH)*DM;
      const u16*  f2w  = w_f2  + (size_t)i*DM*MLPH;

      if (canSwiz)
        k_gemm_bf<128,true,true ><<<dim3(8*nmb), 256, 0, stream>>>(hsbf, inw, xz, 2*DI, DM, nmb);
      else
        k_gemm_bf<128,true,false><<<dim3(8, nmb), 256, 0, stream>>>(hsbf, inw, xz, 2*DI, DM, nmb);
      k_conv1d_silu<<<(Mc*64)/256, 256, 0, stream>>>(xz, cw, cb, xcb);
      k_gemm_bf<64, false,false><<<dim3(1, nmb), 256, 0, stream>>>(xcb, xpw, xdbl, 48, DI, nmb);
      k_scan6<<<dim3(Bc, 8), 512, 0, stream>>>(xdbl, xcb, xz, ybf, Alg, Dpt, dtw, dtb);
      k_gemm_rms<true><<<Mc/128, 512, 0, stream>>>(ybf, outw, residual, n2w, hsbf, DI);
      k_fc1_glu<<<Mc/128, 512, 0, stream>>>(hsbf, f1w, glubf);
      if (i < NL-1)
        k_gemm_rms<true ><<<Mc/128, 512, 0, stream>>>(glubf, f2w, residual,
                                                      norm1_w + (size_t)(i+1)*DM, hsbf, MLPH);
      else
        k_gemm_rms<false><<<Mc/128, 512, 0, stream>>>(glubf, f2w, residual,
                                                      nullptr, nullptr, MLPH);
    }

    k_final_ln<<<Mc/4, 256, 0, stream>>>(residual, normf_w, normf_b, zf);
    k_pool<<<Bc, 1024, 0, stream>>>(zf, mask, pool, b0);
  }
  k_bind<<<B_TOT, 64, 0, stream>>>(pool, bind_w, bind_b, outp);
}